// Round 10
// baseline (247.894 us; speedup 1.0000x reference)
//
#include <hip/hip_runtime.h>

typedef __attribute__((ext_vector_type(8))) short bf8;
typedef __attribute__((ext_vector_type(4))) float f4;
typedef unsigned short u16;

constexpr int B_ = 8, CIN = 256, CINT = 128, NN = 4096;
constexpr float L2E = 1.44269504088896f;

__device__ __forceinline__ u16 f2bf(float f) {
  unsigned int u = __builtin_bit_cast(unsigned int, f);
  u += 0x7FFFu + ((u >> 16) & 1u);   // round-to-nearest-even
  return (u16)(u >> 16);
}

__device__ __forceinline__ void glds16(const void* g, void* l) {
  __builtin_amdgcn_global_load_lds(
      (const __attribute__((address_space(1))) unsigned int*)g,
      (__attribute__((address_space(3))) unsigned int*)l, 16, 0, 0);
}

// pack two f32 -> one u32 of 2 bf16 (RTNE)
__device__ __forceinline__ int cvtpk(float lo, float hi) {
  int r;
  asm("v_cvt_pk_bf16_f32 %0, %1, %2" : "=v"(r) : "v"(lo), "v"(hi));
  return r;
}

// ---------------- prep: f32 weights -> bf16 [mat][128][256]
__global__ __launch_bounds__(256) void prep_kernel(
    const float* __restrict__ wth, const float* __restrict__ wph,
    const float* __restrict__ wg, u16* __restrict__ wbf)
{
  int i = blockIdx.x * 256 + threadIdx.x;          // 0..98303
  const float* src = (i < 32768) ? wth : (i < 65536) ? wph : wg;
  wbf[i] = f2bf(src[i & 32767]);
}

// ---------------- proj (unchanged):
// theta [b][n][128] bf16 row-major.
// phiT  tiled [b][kt=n/32][r=n%32][128d], 16B chunks swizzled c16 ^= (r&7),
//       values pre-scaled by log2(e).
// gTt   tiled [b][kt=n/32][row=d>>1][(d&1)*32+k], 16B chunks c8 ^= (row&7).
__global__ __launch_bounds__(256) void proj_kernel(
    const float* __restrict__ x, const u16* __restrict__ wbf,
    const float* __restrict__ bth, const float* __restrict__ bph,
    const float* __restrict__ bg,
    u16* __restrict__ theta, u16* __restrict__ phiT, u16* __restrict__ gTt)
{
  const int b = blockIdx.y, n0 = blockIdx.x * 64;
  const int tid = threadIdx.x, w = tid >> 6, l = tid & 63;
  const int lr = l & 15, lg = l >> 4;
  __shared__ __align__(16) u16 sx[64 * 256];       // [n][c], swizzled, 32KB

  const float* xb = x + (size_t)b * CIN * NN + n0;
  #pragma unroll
  for (int pass = 0; pass < 8; ++pass) {
    const int cb = w * 8 + pass * 32;
    u16 tmp[8];
    #pragma unroll
    for (int i = 0; i < 8; ++i) tmp[i] = f2bf(xb[(size_t)(cb + i) * NN + l]);
    uint4 v;
    v.x = (unsigned)tmp[0] | ((unsigned)tmp[1] << 16);
    v.y = (unsigned)tmp[2] | ((unsigned)tmp[3] << 16);
    v.z = (unsigned)tmp[4] | ((unsigned)tmp[5] << 16);
    v.w = (unsigned)tmp[6] | ((unsigned)tmp[7] << 16);
    *(uint4*)&sx[l * 256 + (((w + pass * 4) ^ (l & 7)) << 3)] = v;
  }
  __syncthreads();

  #pragma unroll
  for (int dti = 0; dti < 6; ++dti) {
    const int dt = w * 6 + dti;
    const int mat = dt >> 3, d0 = (dt & 7) * 16;
    const float* Bv = (mat == 0) ? bth : (mat == 1) ? bph : bg;
    const u16* wrow = wbf + mat * 32768 + (size_t)(d0 + lr) * 256 + lg * 8;
    bf8 wf[8];
    #pragma unroll
    for (int ks = 0; ks < 8; ++ks) wf[ks] = *(const bf8*)(wrow + ks * 32);

    #pragma unroll
    for (int mt = 0; mt < 4; ++mt) {
      f4 acc = {0.f, 0.f, 0.f, 0.f};
      const int row = mt * 16 + lr;
      #pragma unroll
      for (int ks = 0; ks < 8; ++ks) {
        bf8 bx = *(const bf8*)&sx[row * 256 + (((ks * 4 + lg) ^ (lr & 7)) << 3)];
        acc = __builtin_amdgcn_mfma_f32_16x16x32_bf16(wf[ks], bx, acc, 0, 0, 0);
      }
      const int m = n0 + mt * 16 + lr;
      const int dlo = d0 + lg * 4;
      if (mat == 0) {
        ushort4 h4;
        h4.x = f2bf(acc[0] + Bv[dlo + 0]);
        h4.y = f2bf(acc[1] + Bv[dlo + 1]);
        h4.z = f2bf(acc[2] + Bv[dlo + 2]);
        h4.w = f2bf(acc[3] + Bv[dlo + 3]);
        *(ushort4*)&theta[((size_t)b * NN + m) * CINT + dlo] = h4;
      } else if (mat == 1) {
        const int kt = m >> 5, r32 = m & 31;
        ushort4 h4;
        h4.x = f2bf((acc[0] + Bv[dlo + 0]) * L2E);
        h4.y = f2bf((acc[1] + Bv[dlo + 1]) * L2E);
        h4.z = f2bf((acc[2] + Bv[dlo + 2]) * L2E);
        h4.w = f2bf((acc[3] + Bv[dlo + 3]) * L2E);
        *(ushort4*)&phiT[((size_t)(b * 128 + kt)) * 4096 + r32 * 128 +
                         ((((dlo >> 3) ^ (r32 & 7))) << 3) + (dlo & 7)] = h4;
      } else {
        const int kt = m >> 5, kk = m & 31;
        #pragma unroll
        for (int r = 0; r < 4; ++r) {
          const int d = dlo + r;
          const int grow = d >> 1;
          const int chunk = (((d & 1) * 4 + (kk >> 3)) ^ (grow & 7));
          gTt[((size_t)(b * 128 + kt)) * 4096 + grow * 64 + chunk * 8 + (kk & 7)]
              = f2bf(acc[r] + Bv[d]);
        }
      }
    }
  }
}

// ---------------- attn: 1024 threads = 16 waves = 4 q-waves (32q, qt=2) x
// 4 k-quarters; KT=32; 2-buf glds16; XCD-pinned flat grid (b = bid&7).
__global__ __launch_bounds__(1024, 4) void attn_kernel(
    const u16* __restrict__ theta, const u16* __restrict__ phiT,
    const u16* __restrict__ gTt, float* __restrict__ out)
{
  const int bid = blockIdx.x;
  const int b   = bid & 7;          // XCD-pinned batch
  const int qtl = bid >> 3;         // q-tile 0..31 (128 q each)
  const int t_ = threadIdx.x;
  const int w  = t_ >> 6;
  const int l  = t_ & 63;
  const int lr = l & 15, lg = l >> 4;
  const int qs = w & 3, h = w >> 2;  // q-wave, k-quarter
  const int q0 = qtl * 128 + qs * 32;

  // LDS: phi 4h x 2buf x 8KB (0..64K) | g same (64K..128K) | rs 4KB
  __shared__ __align__(16) char smem[135168];
  u16* sphi_b = (u16*)smem;
  u16* sg_b   = (u16*)(smem + 65536);

  const u16* th = theta + (size_t)b * NN * CINT;
  bf8 qf[2][4];
  #pragma unroll
  for (int qt = 0; qt < 2; ++qt)
    #pragma unroll
    for (int ds = 0; ds < 4; ++ds)
      qf[qt][ds] = *(const bf8*)(th + (size_t)(q0 + qt * 16 + lr) * CINT + ds * 32 + lg * 8);

  f4 y[2][8];
  #pragma unroll
  for (int qt = 0; qt < 2; ++qt)
    #pragma unroll
    for (int dt = 0; dt < 8; ++dt) y[qt][dt] = (f4){0.f, 0.f, 0.f, 0.f};
  float rs[2] = {0.f, 0.f};

  // quarter h covers kt = h*32 .. h*32+31; each wave stages its 2KB slice
  const char* psrc = (const char*)(phiT + (size_t)(b * 128 + h * 32) * 4096) +
                     qs * 2048 + l * 16;
  const char* gsrc = (const char*)(gTt + (size_t)(b * 128 + h * 32) * 4096) +
                     qs * 2048 + l * 16;

  #define STAGE(BUF, T)                                                    \
    {                                                                      \
      const char* sp = psrc + (size_t)(T) * 8192;                          \
      const char* sq = gsrc + (size_t)(T) * 8192;                          \
      char* lp = (char*)sphi_b + (h * 2 + (BUF)) * 8192 + qs * 2048;       \
      char* lq = (char*)sg_b + (h * 2 + (BUF)) * 8192 + qs * 2048;         \
      glds16(sp, lp); glds16(sp + 1024, lp + 1024);                        \
      glds16(sq, lq); glds16(sq + 1024, lq + 1024);                        \
    }

  STAGE(0, 0);
  asm volatile("s_waitcnt vmcnt(0)" ::: "memory");
  __builtin_amdgcn_s_barrier();
  __builtin_amdgcn_sched_barrier(0);

  int cur = 0;
  for (int t = 0; t < 32; ++t) {
    if (t < 31) STAGE(cur ^ 1, t + 1);

    const u16* PH = sphi_b + (h * 2 + cur) * 4096;
    const u16* GG = sg_b + (h * 2 + cur) * 4096;

    // ---- swapped QK^T: A = phi (k rows), B = theta (q rows)
    f4 s[2][2];
    s[0][0] = (f4){0.f,0.f,0.f,0.f}; s[0][1] = (f4){0.f,0.f,0.f,0.f};
    s[1][0] = (f4){0.f,0.f,0.f,0.f}; s[1][1] = (f4){0.f,0.f,0.f,0.f};
    __builtin_amdgcn_s_setprio(1);
    #pragma unroll
    for (int st = 0; st < 2; ++st) {
      const u16* base = PH + (st * 16 + lr) * 128;
      #pragma unroll
      for (int ds = 0; ds < 4; ++ds) {
        bf8 af = *(const bf8*)(base + (((ds * 4 + lg) ^ (lr & 7)) << 3));
        s[0][st] = __builtin_amdgcn_mfma_f32_16x16x32_bf16(af, qf[0][ds], s[0][st], 0, 0, 0);
        s[1][st] = __builtin_amdgcn_mfma_f32_16x16x32_bf16(af, qf[1][ds], s[1][st], 0, 0, 0);
      }
    }
    __builtin_amdgcn_s_setprio(0);

    // ---- g B-fragments (shared across both qt passes)
    bf8 gfr[8];
    #pragma unroll
    for (int dt = 0; dt < 8; ++dt) {
      const int grow = dt * 8 + (lr >> 1);
      const int chunk = (((lr & 1) * 4 + lg) ^ (grow & 7));
      gfr[dt] = *(const bf8*)(GG + grow * 64 + (chunk << 3));
    }

    // ---- per qt: exp2 -> in-register P (cvt_pk + permlane), PV
    #pragma unroll
    for (int qt = 0; qt < 2; ++qt) {
      float p0 = __builtin_amdgcn_exp2f(s[qt][0][0]);
      float p1 = __builtin_amdgcn_exp2f(s[qt][0][1]);
      float p2 = __builtin_amdgcn_exp2f(s[qt][0][2]);
      float p3 = __builtin_amdgcn_exp2f(s[qt][0][3]);
      float p4 = __builtin_amdgcn_exp2f(s[qt][1][0]);
      float p5 = __builtin_amdgcn_exp2f(s[qt][1][1]);
      float p6 = __builtin_amdgcn_exp2f(s[qt][1][2]);
      float p7 = __builtin_amdgcn_exp2f(s[qt][1][3]);
      rs[qt] += ((p0 + p1) + (p2 + p3)) + ((p4 + p5) + (p6 + p7));

      int w0 = cvtpk(p0, p1), w1 = cvtpk(p2, p3);
      int w2 = cvtpk(p4, p5), w3 = cvtpk(p6, p7);
      asm volatile("v_permlane32_swap_b32 %0, %1" : "+v"(w0), "+v"(w2));
      asm volatile("v_permlane16_swap_b32 %0, %1" : "+v"(w0), "+v"(w2));
      asm volatile("v_permlane32_swap_b32 %0, %1" : "+v"(w1), "+v"(w3));
      asm volatile("v_permlane16_swap_b32 %0, %1" : "+v"(w1), "+v"(w3));
      int pai[4] = {w0, w1, w2, w3};
      bf8 paf = __builtin_bit_cast(bf8, *(int4*)pai);

      __builtin_amdgcn_s_setprio(1);
      #pragma unroll
      for (int dt = 0; dt < 8; ++dt)
        y[qt][dt] = __builtin_amdgcn_mfma_f32_16x16x32_bf16(paf, gfr[dt], y[qt][dt], 0, 0, 0);
      __builtin_amdgcn_s_setprio(0);
    }

    asm volatile("s_waitcnt vmcnt(0)" ::: "memory");
    __builtin_amdgcn_s_barrier();
    __builtin_amdgcn_sched_barrier(0);
    cur ^= 1;
  }

  // ---- reduce rs over lg, then combine 4 quarters via LDS (tiles dead)
  #pragma unroll
  for (int qt = 0; qt < 2; ++qt) {
    rs[qt] += __shfl_xor(rs[qt], 16);
    rs[qt] += __shfl_xor(rs[qt], 32);
  }
  __syncthreads();
  float* yc = (float*)smem;                 // 8 slots x 16KB = 128KB
  float* rc = (float*)(smem + 131072);      // 8 slots x 128 f32 = 4KB

  if (h >= 2) {                             // round 1: h2/h3 publish
    const int slot = (h - 2) * 4 + qs;
    #pragma unroll
    for (int qt = 0; qt < 2; ++qt) {
      #pragma unroll
      for (int dt = 0; dt < 8; ++dt)
        *(f4*)&yc[slot * 4096 + (qt * 8 + dt) * 256 + l * 4] = y[qt][dt];
      rc[slot * 128 + qt * 64 + l] = rs[qt];
    }
  }
  __syncthreads();
  if (h < 2) {                              // h0 += h2, h1 += h3
    const int slot = h * 4 + qs;
    #pragma unroll
    for (int qt = 0; qt < 2; ++qt) {
      #pragma unroll
      for (int dt = 0; dt < 8; ++dt)
        y[qt][dt] += *(const f4*)&yc[slot * 4096 + (qt * 8 + dt) * 256 + l * 4];
      rs[qt] += rc[slot * 128 + qt * 64 + l];
    }
  }
  __syncthreads();
  if (h == 1) {                             // round 2: h1 publishes
    #pragma unroll
    for (int qt = 0; qt < 2; ++qt) {
      #pragma unroll
      for (int dt = 0; dt < 8; ++dt)
        *(f4*)&yc[qs * 4096 + (qt * 8 + dt) * 256 + l * 4] = y[qt][dt];
      rc[qs * 128 + qt * 64 + l] = rs[qt];
    }
  }
  __syncthreads();
  if (h == 0) {
    #pragma unroll
    for (int qt = 0; qt < 2; ++qt) {
      #pragma unroll
      for (int dt = 0; dt < 8; ++dt)
        y[qt][dt] += *(const f4*)&yc[qs * 4096 + (qt * 8 + dt) * 256 + l * 4];
      rs[qt] += rc[qs * 128 + qt * 64 + l];
    }
    float* ob = out + (size_t)b * CINT * NN;
    #pragma unroll
    for (int qt = 0; qt < 2; ++qt) {
      f4 rsi;
      #pragma unroll
      for (int r = 0; r < 4; ++r)
        rsi[r] = 1.0f / __shfl(rs[qt], lg * 4 + r, 64);
      #pragma unroll
      for (int dt = 0; dt < 8; ++dt) {
        f4 v = y[qt][dt] * rsi;
        *(float4*)&ob[(size_t)(dt * 16 + lr) * NN + q0 + qt * 16 + lg * 4] = *(float4*)&v;
      }
    }
  }
}

extern "C" void kernel_launch(void* const* d_in, const int* in_sizes, int n_in,
                              void* d_out, int out_size, void* d_ws, size_t ws_size,
                              hipStream_t stream) {
  const float* x   = (const float*)d_in[0];
  const float* wth = (const float*)d_in[1];
  const float* bth = (const float*)d_in[2];
  const float* wph = (const float*)d_in[3];
  const float* bph = (const float*)d_in[4];
  const float* wg  = (const float*)d_in[5];
  const float* bg  = (const float*)d_in[6];
  float* out = (float*)d_out;

  u16* theta = (u16*)d_ws;
  u16* phiT  = theta + (size_t)B_ * NN * CINT;
  u16* gTt   = phiT  + (size_t)B_ * NN * CINT;
  u16* wbf   = gTt   + (size_t)B_ * NN * CINT;

  hipLaunchKernelGGL(prep_kernel, dim3(384), dim3(256), 0, stream, wth, wph, wg, wbf);
  hipLaunchKernelGGL(proj_kernel, dim3(64, 8), dim3(256), 0, stream,
                     x, wbf, bth, bph, bg, theta, phiT, gTt);
  hipLaunchKernelGGL(attn_kernel, dim3(256), dim3(1024), 0, stream,
                     theta, phiT, gTt, out);
}

// Round 11
// 105.307 us; speedup vs baseline: 2.3540x; 2.3540x over previous
//
#include <hip/hip_runtime.h>

typedef __attribute__((ext_vector_type(8))) short bf8;
typedef __attribute__((ext_vector_type(4))) float f4;
typedef unsigned short u16;

constexpr int B_ = 8, CIN = 256, CINT = 128, NN = 4096;
constexpr float L2E = 1.44269504088896f;

__device__ __forceinline__ u16 f2bf(float f) {
  unsigned int u = __builtin_bit_cast(unsigned int, f);
  u += 0x7FFFu + ((u >> 16) & 1u);   // round-to-nearest-even
  return (u16)(u >> 16);
}

__device__ __forceinline__ void glds16(const void* g, void* l) {
  __builtin_amdgcn_global_load_lds(
      (const __attribute__((address_space(1))) unsigned int*)g,
      (__attribute__((address_space(3))) unsigned int*)l, 16, 0, 0);
}

// pack two f32 -> one u32 of 2 bf16 (RTNE)
__device__ __forceinline__ int cvtpk(float lo, float hi) {
  int r;
  asm("v_cvt_pk_bf16_f32 %0, %1, %2" : "=v"(r) : "v"(lo), "v"(hi));
  return r;
}

// ---------------- prep: f32 weights -> bf16 [mat][128][256]
__global__ __launch_bounds__(256) void prep_kernel(
    const float* __restrict__ wth, const float* __restrict__ wph,
    const float* __restrict__ wg, u16* __restrict__ wbf)
{
  int i = blockIdx.x * 256 + threadIdx.x;          // 0..98303
  const float* src = (i < 32768) ? wth : (i < 65536) ? wph : wg;
  wbf[i] = f2bf(src[i & 32767]);
}

// ---------------- proj (Round-5 verified KT=64 formats):
// theta [b][n][128] bf16 row-major.
// phiT  tiled [b][kt=n/64][r=n%64][128d], 16B chunks swizzled c16 ^= (r&7),
//       values pre-scaled by log2(e).
// gTt   tiled [b][kt=n/64][d][64k], 16B chunks swizzled c16 ^= (d&7).
__global__ __launch_bounds__(256) void proj_kernel(
    const float* __restrict__ x, const u16* __restrict__ wbf,
    const float* __restrict__ bth, const float* __restrict__ bph,
    const float* __restrict__ bg,
    u16* __restrict__ theta, u16* __restrict__ phiT, u16* __restrict__ gTt)
{
  const int b = blockIdx.y, n0 = blockIdx.x * 64;
  const int tid = threadIdx.x, w = tid >> 6, l = tid & 63;
  const int lr = l & 15, lg = l >> 4;
  __shared__ __align__(16) u16 sx[64 * 256];       // [n][c], swizzled, 32KB

  const float* xb = x + (size_t)b * CIN * NN + n0;
  #pragma unroll
  for (int pass = 0; pass < 8; ++pass) {
    const int cb = w * 8 + pass * 32;
    u16 tmp[8];
    #pragma unroll
    for (int i = 0; i < 8; ++i) tmp[i] = f2bf(xb[(size_t)(cb + i) * NN + l]);
    uint4 v;
    v.x = (unsigned)tmp[0] | ((unsigned)tmp[1] << 16);
    v.y = (unsigned)tmp[2] | ((unsigned)tmp[3] << 16);
    v.z = (unsigned)tmp[4] | ((unsigned)tmp[5] << 16);
    v.w = (unsigned)tmp[6] | ((unsigned)tmp[7] << 16);
    *(uint4*)&sx[l * 256 + (((w + pass * 4) ^ (l & 7)) << 3)] = v;
  }
  __syncthreads();

  #pragma unroll
  for (int dti = 0; dti < 6; ++dti) {
    const int dt = w * 6 + dti;
    const int mat = dt >> 3, d0 = (dt & 7) * 16;
    const float* Bv = (mat == 0) ? bth : (mat == 1) ? bph : bg;
    const u16* wrow = wbf + mat * 32768 + (size_t)(d0 + lr) * 256 + lg * 8;
    bf8 wf[8];
    #pragma unroll
    for (int ks = 0; ks < 8; ++ks) wf[ks] = *(const bf8*)(wrow + ks * 32);

    #pragma unroll
    for (int mt = 0; mt < 4; ++mt) {
      f4 acc = {0.f, 0.f, 0.f, 0.f};
      const int row = mt * 16 + lr;
      #pragma unroll
      for (int ks = 0; ks < 8; ++ks) {
        bf8 bx = *(const bf8*)&sx[row * 256 + (((ks * 4 + lg) ^ (lr & 7)) << 3)];
        acc = __builtin_amdgcn_mfma_f32_16x16x32_bf16(wf[ks], bx, acc, 0, 0, 0);
      }
      const int m = n0 + mt * 16 + lr;
      const int dlo = d0 + lg * 4;
      if (mat == 0) {
        ushort4 h4;
        h4.x = f2bf(acc[0] + Bv[dlo + 0]);
        h4.y = f2bf(acc[1] + Bv[dlo + 1]);
        h4.z = f2bf(acc[2] + Bv[dlo + 2]);
        h4.w = f2bf(acc[3] + Bv[dlo + 3]);
        *(ushort4*)&theta[((size_t)b * NN + m) * CINT + dlo] = h4;
      } else if (mat == 1) {
        const int kt = m >> 6, rr = m & 63;
        ushort4 h4;
        h4.x = f2bf((acc[0] + Bv[dlo + 0]) * L2E);
        h4.y = f2bf((acc[1] + Bv[dlo + 1]) * L2E);
        h4.z = f2bf((acc[2] + Bv[dlo + 2]) * L2E);
        h4.w = f2bf((acc[3] + Bv[dlo + 3]) * L2E);
        *(ushort4*)&phiT[((size_t)(b * 64 + kt)) * 8192 + rr * 128 +
                         ((((dlo >> 3) ^ (rr & 7))) << 3) + (dlo & 7)] = h4;
      } else {
        const int kt = m >> 6, rr = m & 63;
        #pragma unroll
        for (int r = 0; r < 4; ++r) {
          const int d = dlo + r;
          gTt[((size_t)(b * 64 + kt)) * 8192 + d * 64 +
              (((rr >> 3) ^ (d & 7)) << 3) + (rr & 7)] = f2bf(acc[r] + Bv[d]);
        }
      }
    }
  }
}

// ---------------- attn: 8 waves = 4 q-waves (32 q, qt=2) x 2 k-halves; KT=64.
// 2-buf glds16; in-register P (cvtpk+permlane); XCD-pinned flat grid.
__global__ __launch_bounds__(512, 2) void attn_kernel(
    const u16* __restrict__ theta, const u16* __restrict__ phiT,
    const u16* __restrict__ gTt, float* __restrict__ out)
{
  const int bid = blockIdx.x;
  const int b   = bid & 7;          // XCD-pinned batch
  const int qtl = bid >> 3;         // q-tile 0..31 (128 q each)
  const int t_ = threadIdx.x;
  const int w  = t_ >> 6;
  const int l  = t_ & 63;
  const int lr = l & 15, lg = l >> 4;
  const int h  = w >> 2, wq = w & 3;
  const int qw = qtl * 128 + wq * 32;

  // LDS: phi 2h x 2buf x 16KB (0..64K) | g same (64K..128K); combine reuses.
  __shared__ __align__(16) char smem[131072];
  u16* sphi_b = (u16*)smem;
  u16* sg_b   = (u16*)(smem + 65536);

  const u16* th = theta + (size_t)b * NN * CINT;
  bf8 qf[2][4];
  #pragma unroll
  for (int qt = 0; qt < 2; ++qt)
    #pragma unroll
    for (int ds = 0; ds < 4; ++ds)
      qf[qt][ds] = *(const bf8*)(th + (size_t)(qw + qt * 16 + lr) * CINT + ds * 32 + lg * 8);

  f4 y[2][8];
  #pragma unroll
  for (int qt = 0; qt < 2; ++qt)
    #pragma unroll
    for (int dt = 0; dt < 8; ++dt) y[qt][dt] = (f4){0.f, 0.f, 0.f, 0.f};
  float rs[2] = {0.f, 0.f};

  // half h covers kt = h*32 .. h*32+31 (KT=64 rows); 16KB tiles
  const char* psrc = (const char*)(phiT + (size_t)(b * 64 + h * 32) * 8192) +
                     wq * 4096 + l * 16;
  const char* gsrc = (const char*)(gTt + (size_t)(b * 64 + h * 32) * 8192) +
                     wq * 4096 + l * 16;

  #define STAGE(BUF, T)                                                     \
    {                                                                       \
      const char* sp = psrc + (size_t)(T) * 16384;                          \
      const char* sq = gsrc + (size_t)(T) * 16384;                          \
      char* lp = (char*)sphi_b + (h * 2 + (BUF)) * 16384 + wq * 4096;       \
      char* lq = (char*)sg_b + (h * 2 + (BUF)) * 16384 + wq * 4096;         \
      glds16(sp, lp);        glds16(sp + 1024, lp + 1024);                  \
      glds16(sp + 2048, lp + 2048); glds16(sp + 3072, lp + 3072);           \
      glds16(sq, lq);        glds16(sq + 1024, lq + 1024);                  \
      glds16(sq + 2048, lq + 2048); glds16(sq + 3072, lq + 3072);           \
    }

  STAGE(0, 0);
  asm volatile("s_waitcnt vmcnt(0)" ::: "memory");
  __builtin_amdgcn_s_barrier();
  __builtin_amdgcn_sched_barrier(0);

  int cur = 0;
  for (int t = 0; t < 32; ++t) {
    if (t < 31) STAGE(cur ^ 1, t + 1);

    const u16* PH = sphi_b + (h * 2 + cur) * 8192;
    const u16* GG = sg_b + (h * 2 + cur) * 8192;

    // ---- swapped QK^T: A = phi (k rows), B = theta (q rows); 4 S-tiles
    f4 s[2][4];
    #pragma unroll
    for (int qt = 0; qt < 2; ++qt)
      #pragma unroll
      for (int st = 0; st < 4; ++st) s[qt][st] = (f4){0.f, 0.f, 0.f, 0.f};
    __builtin_amdgcn_s_setprio(1);
    #pragma unroll
    for (int st = 0; st < 4; ++st) {
      const u16* base = PH + (st * 16 + lr) * 128;
      #pragma unroll
      for (int ds = 0; ds < 4; ++ds) {
        bf8 af = *(const bf8*)(base + (((ds * 4 + lg) ^ (lr & 7)) << 3));
        s[0][st] = __builtin_amdgcn_mfma_f32_16x16x32_bf16(af, qf[0][ds], s[0][st], 0, 0, 0);
        s[1][st] = __builtin_amdgcn_mfma_f32_16x16x32_bf16(af, qf[1][ds], s[1][st], 0, 0, 0);
      }
    }
    __builtin_amdgcn_s_setprio(0);

    // ---- per qt: exp2 -> in-register P A-frags, one per k-32 slab
    bf8 paf[2][2];
    #pragma unroll
    for (int qt = 0; qt < 2; ++qt) {
      #pragma unroll
      for (int pr = 0; pr < 2; ++pr) {     // pair (st 2pr, 2pr+1) -> k slab pr
        float p0 = __builtin_amdgcn_exp2f(s[qt][2 * pr][0]);
        float p1 = __builtin_amdgcn_exp2f(s[qt][2 * pr][1]);
        float p2 = __builtin_amdgcn_exp2f(s[qt][2 * pr][2]);
        float p3 = __builtin_amdgcn_exp2f(s[qt][2 * pr][3]);
        float p4 = __builtin_amdgcn_exp2f(s[qt][2 * pr + 1][0]);
        float p5 = __builtin_amdgcn_exp2f(s[qt][2 * pr + 1][1]);
        float p6 = __builtin_amdgcn_exp2f(s[qt][2 * pr + 1][2]);
        float p7 = __builtin_amdgcn_exp2f(s[qt][2 * pr + 1][3]);
        rs[qt] += ((p0 + p1) + (p2 + p3)) + ((p4 + p5) + (p6 + p7));

        int w0 = cvtpk(p0, p1), w1 = cvtpk(p2, p3);
        int w2 = cvtpk(p4, p5), w3 = cvtpk(p6, p7);
        asm volatile("v_permlane32_swap_b32 %0, %1" : "+v"(w0), "+v"(w2));
        asm volatile("v_permlane16_swap_b32 %0, %1" : "+v"(w0), "+v"(w2));
        asm volatile("v_permlane32_swap_b32 %0, %1" : "+v"(w1), "+v"(w3));
        asm volatile("v_permlane16_swap_b32 %0, %1" : "+v"(w1), "+v"(w3));
        int pai[4] = {w0, w1, w2, w3};
        paf[qt][pr] = __builtin_bit_cast(bf8, *(int4*)pai);
      }
    }

    // ---- PV: A = P (q rows), B = g (d rows); g frag shared across qt
    __builtin_amdgcn_s_setprio(1);
    #pragma unroll
    for (int ks = 0; ks < 2; ++ks) {
      #pragma unroll
      for (int dt = 0; dt < 8; ++dt) {
        bf8 gf = *(const bf8*)(GG + (dt * 16 + lr) * 64 +
                               (((ks * 4 + lg) ^ (lr & 7)) << 3));
        y[0][dt] = __builtin_amdgcn_mfma_f32_16x16x32_bf16(paf[0][ks], gf, y[0][dt], 0, 0, 0);
        y[1][dt] = __builtin_amdgcn_mfma_f32_16x16x32_bf16(paf[1][ks], gf, y[1][dt], 0, 0, 0);
      }
    }
    __builtin_amdgcn_s_setprio(0);

    asm volatile("s_waitcnt vmcnt(0)" ::: "memory");
    __builtin_amdgcn_s_barrier();
    __builtin_amdgcn_sched_barrier(0);
    cur ^= 1;
  }

  // ---- reduce rs over lg, then combine 2 k-halves via LDS (tiles dead)
  #pragma unroll
  for (int qt = 0; qt < 2; ++qt) {
    rs[qt] += __shfl_xor(rs[qt], 16);
    rs[qt] += __shfl_xor(rs[qt], 32);
  }
  __syncthreads();
  float* yc = (float*)smem;                 // 4 wq x 16KB
  float* rc = (float*)(smem + 65536);       // small, in dead sg region
  if (h == 1) {
    #pragma unroll
    for (int qt = 0; qt < 2; ++qt) {
      #pragma unroll
      for (int dt = 0; dt < 8; ++dt)
        *(f4*)&yc[wq * 4096 + (qt * 8 + dt) * 256 + l * 4] = y[qt][dt];
      rc[wq * 128 + qt * 64 + l] = rs[qt];
    }
  }
  __syncthreads();
  if (h == 0) {
    #pragma unroll
    for (int qt = 0; qt < 2; ++qt) {
      #pragma unroll
      for (int dt = 0; dt < 8; ++dt)
        y[qt][dt] += *(const f4*)&yc[wq * 4096 + (qt * 8 + dt) * 256 + l * 4];
      rs[qt] += rc[wq * 128 + qt * 64 + l];
    }
    float* ob = out + (size_t)b * CINT * NN;
    #pragma unroll
    for (int qt = 0; qt < 2; ++qt) {
      f4 rsi;
      #pragma unroll
      for (int r = 0; r < 4; ++r)
        rsi[r] = 1.0f / __shfl(rs[qt], lg * 4 + r, 64);
      #pragma unroll
      for (int dt = 0; dt < 8; ++dt) {
        f4 v = y[qt][dt] * rsi;
        *(float4*)&ob[(size_t)(dt * 16 + lr) * NN + qw + qt * 16 + lg * 4] = *(float4*)&v;
      }
    }
  }
}

extern "C" void kernel_launch(void* const* d_in, const int* in_sizes, int n_in,
                              void* d_out, int out_size, void* d_ws, size_t ws_size,
                              hipStream_t stream) {
  const float* x   = (const float*)d_in[0];
  const float* wth = (const float*)d_in[1];
  const float* bth = (const float*)d_in[2];
  const float* wph = (const float*)d_in[3];
  const float* bph = (const float*)d_in[4];
  const float* wg  = (const float*)d_in[5];
  const float* bg  = (const float*)d_in[6];
  float* out = (float*)d_out;

  u16* theta = (u16*)d_ws;
  u16* phiT  = theta + (size_t)B_ * NN * CINT;
  u16* gTt   = phiT  + (size_t)B_ * NN * CINT;
  u16* wbf   = gTt   + (size_t)B_ * NN * CINT;

  hipLaunchKernelGGL(prep_kernel, dim3(384), dim3(256), 0, stream, wth, wph, wg, wbf);
  hipLaunchKernelGGL(proj_kernel, dim3(64, 8), dim3(256), 0, stream,
                     x, wbf, bth, bph, bg, theta, phiT, gTt);
  hipLaunchKernelGGL(attn_kernel, dim3(256), dim3(512), 0, stream,
                     theta, phiT, gTt, out);
}